// Round 7
// baseline (784.107 us; speedup 1.0000x reference)
//
#include <hip/hip_runtime.h>

#define KK 27
#define EPSV 1e-5f

typedef __attribute__((ext_vector_type(8))) short bf16x8;
typedef __attribute__((ext_vector_type(4))) float f32x4;
typedef __attribute__((ext_vector_type(2))) float f32x2;
typedef __attribute__((ext_vector_type(4))) unsigned int u32x4;

static __device__ __forceinline__ unsigned short f2bf(float f) {
    unsigned u = __float_as_uint(f);
    u = u + 0x7fffu + ((u >> 16) & 1u);
    return (unsigned short)(u >> 16);
}
static __device__ __forceinline__ float bflo(unsigned u) { return __uint_as_float(u << 16); }
static __device__ __forceinline__ float bfhi(unsigned u) { return __uint_as_float(u & 0xffff0000u); }
static __device__ __forceinline__ f32x2 unpack2(unsigned u) {
    f32x2 r; r.x = bflo(u); r.y = bfhi(u); return r;
}

// --- K0: transpose+convert W1[m][k][n] (fp32) -> WT[m][n][k] (bf16) ---
__global__ void k0_wt(const float* __restrict__ W1, unsigned short* __restrict__ WT) {
    int m = blockIdx.x >> 7, n = blockIdx.x & 127, k = threadIdx.x;
    WT[((m * 128 + n) * 128) + k] = f2bf(W1[(m * 128 + k) * 128 + n]);
}

// --- KA v2: 128-row tile; B-frags direct from L2-hot WT (no Bs stage);
//     A-frags hoisted across the 4-m loop; 2-phase LDS bounce for coalesced H stores.
//     Writes raw y bf16 into Yall[row][m*128+c] (row stride 512) + col stats.
__launch_bounds__(256)
__global__ void kA_gemm(const float* __restrict__ x, const unsigned short* __restrict__ WT,
                        unsigned short* __restrict__ Yall, float* __restrict__ ysum,
                        float* __restrict__ ysq, int N) {
    __shared__ unsigned short As[128 * 136];  // [row][k], pad 8 -> 34816 B
    __shared__ unsigned short Ys[64 * 136];   // half-tile bounce  -> 17408 B
    const int t = threadIdx.x;
    const int i0 = blockIdx.x * 128;

    // stage A: 128 rows x 128 k, fp32 -> bf16
#pragma unroll
    for (int it = 0; it < 16; ++it) {
        int flat = it * 256 + t;
        int r = flat >> 5, c4 = (flat & 31) * 4;
        float4 v = make_float4(0.f, 0.f, 0.f, 0.f);
        if (i0 + r < N) v = *(const float4*)(x + (size_t)(i0 + r) * 128 + c4);
        ushort4 bb;
        bb.x = f2bf(v.x); bb.y = f2bf(v.y); bb.z = f2bf(v.z); bb.w = f2bf(v.w);
        *(ushort4*)(As + r * 136 + c4) = bb;
    }
    __syncthreads();

    const int w = t >> 6, lane = t & 63;
    const int r16 = lane & 15, q = lane >> 4;

    // hoist A-frags: wave w covers rows [w*32, w*32+32) -> 2 row-tiles x 4 ks
    bf16x8 Afr[4][2];
#pragma unroll
    for (int ks = 0; ks < 4; ++ks)
#pragma unroll
        for (int mt = 0; mt < 2; ++mt)
            Afr[ks][mt] = *(const bf16x8*)(As + (w * 32 + mt * 16 + r16) * 136 + ks * 32 + q * 8);

    for (int m = 0; m < 4; ++m) {
        f32x4 acc[2][8];
#pragma unroll
        for (int a = 0; a < 2; ++a)
#pragma unroll
            for (int b = 0; b < 8; ++b) { acc[a][b][0]=0.f; acc[a][b][1]=0.f; acc[a][b][2]=0.f; acc[a][b][3]=0.f; }

        const unsigned short* Wm = WT + (size_t)m * 16384;
#pragma unroll
        for (int ks = 0; ks < 4; ++ks) {
            bf16x8 Bfr[8];
#pragma unroll
            for (int ci = 0; ci < 8; ++ci)
                Bfr[ci] = *(const bf16x8*)(Wm + (ci * 16 + r16) * 128 + ks * 32 + q * 8);
#pragma unroll
            for (int mt = 0; mt < 2; ++mt)
#pragma unroll
                for (int ci = 0; ci < 8; ++ci)
                    acc[mt][ci] = __builtin_amdgcn_mfma_f32_16x16x32_bf16(Afr[ks][mt], Bfr[ci], acc[mt][ci], 0, 0, 0);
        }

        // column stats
#pragma unroll
        for (int ci = 0; ci < 8; ++ci) {
            float s = 0.f, s2 = 0.f;
#pragma unroll
            for (int mt = 0; mt < 2; ++mt) {
#pragma unroll
                for (int r = 0; r < 4; ++r) {
                    int row = i0 + w * 32 + mt * 16 + q * 4 + r;
                    float vv = acc[mt][ci][r];
                    if (row < N) { s += vv; s2 += vv * vv; }
                }
            }
            s  += __shfl_xor(s, 16);  s  += __shfl_xor(s, 32);
            s2 += __shfl_xor(s2, 16); s2 += __shfl_xor(s2, 32);
            if (lane < 16) {
                int col = ci * 16 + r16;
                atomicAdd(ysum + m * 128 + col, s);
                atomicAdd(ysq  + m * 128 + col, s2);
            }
        }

        // 2-phase bounce + coalesced NT store (phase ph covers global rows i0+ph*64..+63)
#pragma unroll
        for (int ph = 0; ph < 2; ++ph) {
            __syncthreads();
            if ((w >> 1) == ph) {
#pragma unroll
                for (int mt = 0; mt < 2; ++mt)
#pragma unroll
                    for (int ci = 0; ci < 8; ++ci)
#pragma unroll
                        for (int r = 0; r < 4; ++r) {
                            int rl = (w & 1) * 32 + mt * 16 + q * 4 + r;
                            Ys[rl * 136 + ci * 16 + r16] = f2bf(acc[mt][ci][r]);
                        }
            }
            __syncthreads();
#pragma unroll
            for (int it = 0; it < 4; ++it) {
                int chunk = it * 256 + t;
                int row = chunk >> 4, c8 = (chunk & 15) * 8;
                int grow = i0 + ph * 64 + row;
                if (grow < N) {
                    u32x4 v = *(const u32x4*)(Ys + row * 136 + c8);
                    __builtin_nontemporal_store(v, (u32x4*)(Yall + (size_t)grow * 512 + m * 128 + c8));
                }
            }
        }
    }
}

// --- K2: finalize BN1 coefficients (blockDim = 512 = 128*4) ---
__global__ void k2_coef(const float* __restrict__ ysum, const float* __restrict__ ysq,
                        const float* __restrict__ g1, const float* __restrict__ b1,
                        float* __restrict__ a1, float* __restrict__ c1, int N) {
    int c = threadIdx.x & 127;
    int m = threadIdx.x >> 7;
    float mean = ysum[m * 128 + c] / (float)N;
    float var  = ysq[m * 128 + c] / (float)N - mean * mean;
    float a = g1[m * 128 + c] * rsqrtf(var + EPSV);
    a1[m * 128 + c] = a;
    c1[m * 128 + c] = b1[m * 128 + c] - mean * a;
}

// --- K4_ALL v3: merged gather, one voxel per wave, packed-f32 inner math.
//     lane: m = lane>>4, c16 = lane&15. Cross-m sum via shfl_xor(16,32).
__launch_bounds__(256)
__global__ void k4_all(const unsigned short* __restrict__ Yall, const int* __restrict__ nbr,
                       const float* __restrict__ wkg, const float* __restrict__ a1,
                       const float* __restrict__ c1, float* __restrict__ P,
                       float* __restrict__ osum, float* __restrict__ osq, int N) {
    __shared__ unsigned short wkL[4 * KK * 136];   // bf16 [m*27+k][c] pad 8
    __shared__ float ssum[128], ssq[128];
    const int t = threadIdx.x;
    for (int idx = t; idx < 4 * KK * 128; idx += 256) {
        int c = idx & 127, km = idx >> 7;
        wkL[km * 136 + c] = f2bf(wkg[idx]);
    }
    if (t < 128) { ssum[t] = 0.f; ssq[t] = 0.f; }

    const int lane = t & 63;
    const int m = lane >> 4, c16 = lane & 15;

    // BN coefficients for this lane's branch m, channels c16*8..+8, packed f32x2
    f32x2 A2[4], C2[4];
    {
        const float* ap = a1 + m * 128 + c16 * 8;
        const float* cp = c1 + m * 128 + c16 * 8;
#pragma unroll
        for (int p = 0; p < 4; ++p) {
            A2[p].x = ap[2 * p]; A2[p].y = ap[2 * p + 1];
            C2[p].x = cp[2 * p]; C2[p].y = cp[2 * p + 1];
        }
    }
    __syncthreads();

    f32x2 os2[4], oq2[4];
#pragma unroll
    for (int p = 0; p < 4; ++p) { os2[p] = (f32x2)0.f; oq2[p] = (f32x2)0.f; }
    const f32x2 zero2 = (f32x2)0.f;

    const int wid = blockIdx.x * 4 + (t >> 6);
    const int nw  = gridDim.x * 4;
    for (int vox = wid; vox < N; vox += nw) {
        const int sv = __builtin_amdgcn_readfirstlane(vox);
        const int* np = nbr + (size_t)sv * KK;     // wave-uniform -> s_load
        f32x2 acc2[4];
#pragma unroll
        for (int p = 0; p < 4; ++p) acc2[p] = (f32x2)0.f;

#pragma unroll 4
        for (int k = 0; k < KK; ++k) {
            const int j = np[k];
            const uint4 hv = *(const uint4*)(Yall + ((size_t)j << 9) + lane * 8);
            const uint4 wv = *(const uint4*)(wkL + (m * KK + k) * 136 + c16 * 8);
            const unsigned hu[4] = {hv.x, hv.y, hv.z, hv.w};
            const unsigned wu[4] = {wv.x, wv.y, wv.z, wv.w};
#pragma unroll
            for (int p = 0; p < 4; ++p) {
                f32x2 y = unpack2(hu[p]);
                f32x2 wf = unpack2(wu[p]);
                f32x2 h = y * A2[p] + C2[p];          // v_pk_fma_f32
                h = __builtin_elementwise_max(h, zero2);
                acc2[p] += h * wf;                     // v_pk_fma_f32
            }
        }

        // sum over the 4 branches (lanes {l, l^16, l^32, l^48})
#pragma unroll
        for (int p = 0; p < 4; ++p) {
            acc2[p].x += __shfl_xor(acc2[p].x, 16); acc2[p].x += __shfl_xor(acc2[p].x, 32);
            acc2[p].y += __shfl_xor(acc2[p].y, 16); acc2[p].y += __shfl_xor(acc2[p].y, 32);
        }

        if (lane < 16) {
            f32x4 v0, v1;
            v0[0] = acc2[0].x; v0[1] = acc2[0].y; v0[2] = acc2[1].x; v0[3] = acc2[1].y;
            v1[0] = acc2[2].x; v1[1] = acc2[2].y; v1[2] = acc2[3].x; v1[3] = acc2[3].y;
            float* p = P + (size_t)vox * 128 + c16 * 8;
            __builtin_nontemporal_store(v0, (f32x4*)p);
            __builtin_nontemporal_store(v1, (f32x4*)(p + 4));
#pragma unroll
            for (int pp = 0; pp < 4; ++pp) {
                os2[pp] += acc2[pp];
                oq2[pp] += acc2[pp] * acc2[pp];
            }
        }
    }

    if (lane < 16) {
#pragma unroll
        for (int p = 0; p < 4; ++p) {
            atomicAdd(ssum + c16 * 8 + 2 * p,     os2[p].x);
            atomicAdd(ssum + c16 * 8 + 2 * p + 1, os2[p].y);
            atomicAdd(ssq  + c16 * 8 + 2 * p,     oq2[p].x);
            atomicAdd(ssq  + c16 * 8 + 2 * p + 1, oq2[p].y);
        }
    }
    __syncthreads();
    if (t < 128) {
        atomicAdd(osum + t, ssum[t]);
        atomicAdd(osq  + t, ssq[t]);
    }
}

// --- K5: finalize output BN coefficients ---
__global__ void k5_coef(const float* __restrict__ osum, const float* __restrict__ osq,
                        const float* __restrict__ g, const float* __restrict__ b,
                        float* __restrict__ ao, float* __restrict__ co, int N) {
    int c = threadIdx.x;
    float mean = osum[c] / (float)N;
    float var  = osq[c] / (float)N - mean * mean;
    float a = g[c] * rsqrtf(var + EPSV);
    ao[c] = a;
    co[c] = b[c] - mean * a;
}

// --- K6: out = relu(relu(P*a + c) + x), in-place on d_out, NT traffic ---
__launch_bounds__(256)
__global__ void k6_final(float* __restrict__ P, const float* __restrict__ x,
                         const float* __restrict__ ao, const float* __restrict__ co, int N) {
    long long t4 = ((long long)blockIdx.x * 256 + threadIdx.x) * 4;
    if (t4 >= (long long)N * 128) return;
    int c4 = (int)(t4 & 127);
    f32x4 p  = __builtin_nontemporal_load((const f32x4*)(P + t4));
    f32x4 xv = __builtin_nontemporal_load((const f32x4*)(x + t4));
    const float4 a = *(const float4*)(ao + c4);
    const float4 c = *(const float4*)(co + c4);
    f32x4 o;
    o[0] = fmaxf(0.f, fmaxf(0.f, p[0] * a.x + c.x) + xv[0]);
    o[1] = fmaxf(0.f, fmaxf(0.f, p[1] * a.y + c.y) + xv[1]);
    o[2] = fmaxf(0.f, fmaxf(0.f, p[2] * a.z + c.z) + xv[2]);
    o[3] = fmaxf(0.f, fmaxf(0.f, p[3] * a.w + c.w) + xv[3]);
    __builtin_nontemporal_store(o, (f32x4*)(P + t4));
}

extern "C" void kernel_launch(void* const* d_in, const int* in_sizes, int n_in,
                              void* d_out, int out_size, void* d_ws, size_t ws_size,
                              hipStream_t stream) {
    const float* x     = (const float*)d_in[0];
    const int*   nbr   = (const int*)d_in[1];
    const float* W1    = (const float*)d_in[2];
    const float* g1    = (const float*)d_in[3];
    const float* b1    = (const float*)d_in[4];
    const float* wk    = (const float*)d_in[5];
    const float* g_out = (const float*)d_in[6];
    const float* b_out = (const float*)d_in[7];
    const int N = in_sizes[0] / 128;

    float* P = (float*)d_out;
    char* ws = (char*)d_ws;
    float* ysum = (float*)ws;          // [512]
    float* ysq  = ysum + 512;          // [512]
    float* osum = ysq + 512;           // [128]
    float* osq  = osum + 128;          // [128]
    float* a1   = osq + 128;           // [512]
    float* c1   = a1 + 512;            // [512]
    float* ao   = c1 + 512;            // [128]
    float* co   = ao + 128;            // [128]
    unsigned short* WT = (unsigned short*)(ws + 16384);            // 4*128*128 bf16
    unsigned short* Y  = (unsigned short*)(ws + 16384 + 131072);   // N*512 bf16 interleaved

    hipMemsetAsync(d_ws, 0, 5120, stream);
    k0_wt<<<512, 128, 0, stream>>>(W1, WT);

    const int gA = (N + 127) / 128;
    kA_gemm<<<gA, 256, 0, stream>>>(x, WT, Y, ysum, ysq, N);
    k2_coef<<<1, 512, 0, stream>>>(ysum, ysq, g1, b1, a1, c1, N);
    k4_all<<<1280, 256, 0, stream>>>(Y, nbr, wk, a1, c1, P, osum, osq, N);
    k5_coef<<<1, 128, 0, stream>>>(osum, osq, g_out, b_out, ao, co, N);
    const int g6 = (int)(((long long)N * 128 / 4 + 255) / 256);
    k6_final<<<g6, 256, 0, stream>>>(P, x, ao, co, N);
}